// Round 1
// baseline (891.019 us; speedup 1.0000x reference)
//
#include <hip/hip_runtime.h>

#define BLOCK  256
#define ITEMS  16
#define CHUNK  (BLOCK * ITEMS)   // 4096 elements per block
#define NBATCH 8
#define MAXLEN 256000
#define CROW4  16                // float4 per 64-float row

// ---------------- Kernel 1: per-block histogram of inds[:,0] ----------------
__global__ __launch_bounds__(BLOCK) void hist_kernel(const int4* __restrict__ inds,
                                                     int n,
                                                     int* __restrict__ blockCounts) {
    int base = blockIdx.x * CHUNK;
    __shared__ int cnt[NBATCH];
    if (threadIdx.x < NBATCH) cnt[threadIdx.x] = 0;
    __syncthreads();

    // packed 8 x 8-bit per-thread counters (max 16 per field)
    unsigned long long p8 = 0;
#pragma unroll
    for (int k = 0; k < ITEMS; ++k) {
        int idx = base + k * BLOCK + threadIdx.x;   // coalesced int4 loads
        if (idx < n) {
            int b = inds[idx].x;
            p8 += 1ull << (8 * b);
        }
    }
    // expand to 2 x (4 x 16-bit) so a 64-lane sum (max 1024/field) can't overflow
    unsigned long long lo = 0, hi = 0;
#pragma unroll
    for (int j = 0; j < 4; ++j) {
        lo |= ((p8 >> (8 * j)) & 0xFFull) << (16 * j);
        hi |= ((p8 >> (8 * (j + 4))) & 0xFFull) << (16 * j);
    }
#pragma unroll
    for (int d = 1; d < 64; d <<= 1) {
        lo += __shfl_xor(lo, d, 64);
        hi += __shfl_xor(hi, d, 64);
    }
    int lane = threadIdx.x & 63;
    if (lane == 0) {
#pragma unroll
        for (int j = 0; j < 4; ++j) {
            atomicAdd(&cnt[j],     (int)((lo >> (16 * j)) & 0xFFFFull));
            atomicAdd(&cnt[j + 4], (int)((hi >> (16 * j)) & 0xFFFFull));
        }
    }
    __syncthreads();
    if (threadIdx.x < NBATCH)
        blockCounts[blockIdx.x * NBATCH + threadIdx.x] = cnt[threadIdx.x];
}

// -------- Kernel 2: exclusive scan over blocks, one wave per batch ----------
__global__ __launch_bounds__(512) void scan_kernel(const int* __restrict__ blockCounts,
                                                   int numBlocks,
                                                   int* __restrict__ blockOffsets,
                                                   int* __restrict__ totals) {
    int w = threadIdx.x >> 6;      // batch = wave id (8 waves)
    int lane = threadIdx.x & 63;
    int carry = 0;
    for (int c = 0; c < numBlocks; c += 64) {
        int i = c + lane;
        int v = (i < numBlocks) ? blockCounts[i * NBATCH + w] : 0;
        int x = v;
#pragma unroll
        for (int d = 1; d < 64; d <<= 1) {
            int y = __shfl_up(x, d, 64);
            if (lane >= d) x += y;
        }
        if (i < numBlocks) blockOffsets[i * NBATCH + w] = carry + x - v;
        carry += __shfl(x, 63, 64);
    }
    if (lane == 0) totals[w] = carry;
}

// -------- Kernel 3: zero only the unused tail rows of each batch ------------
__global__ __launch_bounds__(BLOCK) void zero_tail_kernel(float4* __restrict__ out,
                                                          const int* __restrict__ totals) {
    int b = blockIdx.y;
    int cnt = totals[b];
    if (cnt > MAXLEN) cnt = MAXLEN;
    int start = (b * MAXLEN + cnt) * CROW4;       // float4 units, fits in int (32.8M max)
    int end   = (b + 1) * MAXLEN * CROW4;
    float4 z = make_float4(0.f, 0.f, 0.f, 0.f);
    for (int i = start + blockIdx.x * BLOCK + threadIdx.x; i < end; i += gridDim.x * BLOCK)
        out[i] = z;
}

// -------- Kernel 4: stable in-block rank + cooperative row scatter ----------
__global__ __launch_bounds__(BLOCK) void scatter_kernel(const int4*  __restrict__ inds,
                                                        const float4* __restrict__ feat,
                                                        const int*   __restrict__ blockOffsets,
                                                        float4* __restrict__ out,
                                                        int n) {
    __shared__ int bsh[CHUNK];                 // batch id per element (16 KB)
    __shared__ int dsh[CHUNK];                 // dst row per element  (16 KB)
    __shared__ int off[BLOCK * 9];             // per-thread per-batch base (padded, 9 KB)
    __shared__ int boff[NBATCH];
    __shared__ unsigned long long wlo[4], whi[4];

    int tid = threadIdx.x;
    int base = blockIdx.x * CHUNK;
    if (tid < NBATCH) boff[tid] = blockOffsets[blockIdx.x * NBATCH + tid];

    // stage b values into LDS with coalesced int4 loads
#pragma unroll
    for (int k = 0; k < ITEMS; ++k) {
        int idx = base + k * BLOCK + tid;
        bsh[k * BLOCK + tid] = (idx < n) ? inds[idx].x : -1;
    }
    __syncthreads();

    // per-thread counts of its 16 CONTIGUOUS elements (preserves stable order)
    int s = tid * ITEMS;
    unsigned long long p8 = 0;
#pragma unroll
    for (int j = 0; j < ITEMS; ++j) {
        int b = bsh[s + j];
        if (b >= 0) p8 += 1ull << (8 * b);
    }
    unsigned long long lo = 0, hi = 0;
#pragma unroll
    for (int j = 0; j < 4; ++j) {
        lo |= ((p8 >> (8 * j)) & 0xFFull) << (16 * j);
        hi |= ((p8 >> (8 * (j + 4))) & 0xFFull) << (16 * j);
    }

    // 64-lane inclusive scan of packed 16-bit fields (block max 4096 < 65536)
    unsigned long long slo = lo, shi = hi;
    int lane = tid & 63, wave = tid >> 6;
#pragma unroll
    for (int d = 1; d < 64; d <<= 1) {
        unsigned long long tlo = __shfl_up(slo, d, 64);
        unsigned long long thi = __shfl_up(shi, d, 64);
        if (lane >= d) { slo += tlo; shi += thi; }
    }
    if (lane == 63) { wlo[wave] = slo; whi[wave] = shi; }
    __syncthreads();
    unsigned long long plo = slo - lo, phi = shi - hi;   // exclusive within wave
#pragma unroll
    for (int w = 0; w < 4; ++w)
        if (w < wave) { plo += wlo[w]; phi += whi[w]; }

    // per-thread per-batch starting rank (global): block offset + in-block exclusive
#pragma unroll
    for (int j = 0; j < 4; ++j) {
        off[tid * 9 + j]     = boff[j]     + (int)((plo >> (16 * j)) & 0xFFFF);
        off[tid * 9 + j + 4] = boff[j + 4] + (int)((phi >> (16 * j)) & 0xFFFF);
    }

    // assign destination rows in original order
#pragma unroll
    for (int j = 0; j < ITEMS; ++j) {
        int e = s + j;
        int b = bsh[e];
        if (b >= 0) {
            int r = off[tid * 9 + b]++;          // owner-thread LDS RMW, no races
            dsh[e] = (r < MAXLEN) ? (b * MAXLEN + r) : -1;
        } else {
            dsh[e] = -1;
        }
    }
    __syncthreads();

    // cooperative copy: 16 lanes per row (16 x float4 = 256 B), 16 rows/iter.
    // Reads: wave covers 4 consecutive rows = 1 KB contiguous. Writes: 256 B
    // chunks, sequential within each batch stream.
    int lane16 = tid & 15;
    int rg = tid >> 4;                           // 0..15
    for (int r0 = 0; r0 < CHUNK; r0 += 16) {
        int e = r0 + rg;
        int dst = dsh[e];
        if (dst >= 0) {
            int src = base + e;
            out[dst * CROW4 + lane16] = feat[src * CROW4 + lane16];
        }
    }
}

extern "C" void kernel_launch(void* const* d_in, const int* in_sizes, int n_in,
                              void* d_out, int out_size, void* d_ws, size_t ws_size,
                              hipStream_t stream) {
    const int4*   inds = (const int4*)d_in[0];
    const float4* feat = (const float4*)d_in[1];
    float4* out = (float4*)d_out;
    int n = in_sizes[0] / 4;                     // N = 2,000,000
    int numBlocks = (n + CHUNK - 1) / CHUNK;     // 489

    int* blockCounts  = (int*)d_ws;
    int* blockOffsets = blockCounts + numBlocks * NBATCH;
    int* totals       = blockOffsets + numBlocks * NBATCH;

    hist_kernel<<<numBlocks, BLOCK, 0, stream>>>(inds, n, blockCounts);
    scan_kernel<<<1, 512, 0, stream>>>(blockCounts, numBlocks, blockOffsets, totals);
    zero_tail_kernel<<<dim3(64, NBATCH), BLOCK, 0, stream>>>(out, totals);
    scatter_kernel<<<numBlocks, BLOCK, 0, stream>>>(inds, feat, blockOffsets, out, n);
}